// Round 1
// 1210.843 us; speedup vs baseline: 1.1164x; 1.1164x over previous
//
#include <hip/hip_runtime.h>
#include <cstdint>

typedef unsigned short u16;
typedef __attribute__((ext_vector_type(8))) __bf16 bf16x8;
typedef __attribute__((ext_vector_type(4))) float f32x4;
typedef __attribute__((ext_vector_type(4))) unsigned short u16x4;

// round-to-nearest-even f32 -> bf16 bits (inputs are finite randn; no NaN path)
__device__ __forceinline__ u16 f2bf(float f) {
  unsigned u = __float_as_uint(f);
  u += 0x7fff + ((u >> 16) & 1);
  return (u16)(u >> 16);
}

__device__ __forceinline__ void g2l16(const void* g, void* l) {
  __builtin_amdgcn_global_load_lds(
      (const __attribute__((address_space(1))) unsigned int*)g,
      (__attribute__((address_space(3))) unsigned int*)l, 16, 0, 0);
}

// LDS XOR swizzle (T2): permute 16B slots (bits 4-6) by row-pair bits (7-9).
// Applied as: linear global_load_lds dest + inverse-swizzled global SOURCE +
// swizzled ds_read address (both-sides-or-neither, rule #21). Involution.
__device__ __forceinline__ int swz(int q) { return q ^ (((q >> 7) & 7) << 4); }

// ---------------------------------------------------------------------------
// NT GEMM, 256x256 tile, 8-phase-style pipelined schedule (T1+T2+T3+T4+T5):
//   C[m][n] = scale * sum_k A[m][k] * B[n][k]   (A,B bf16, f32 acc)
// 512 threads = 8 waves (2Mx4N), per-wave 128x64 output (8x4 mfma 16x16x32).
// LDS: ring of 4 K-tiles (BK=32): A[4][256][32] | B[4][256][32] = 128 KiB.
// Pipeline: stage K-tile tau+3 during tau's two phases; s_waitcnt vmcnt(8)
// once per K-tile => tile tau+1 landed, tau+2/tau+3 (8 loads) stay in flight.
// Requires K % 32 == 0 and K/32 >= 4 (here K = 1024 or 2048).
// ---------------------------------------------------------------------------
template <int OUT_BF16>
__global__ __launch_bounds__(512, 2)
void gemm_nt_8p(const u16* __restrict__ A, const u16* __restrict__ B,
                void* __restrict__ Cv,
                int lda, int ldb, int ldc,
                long sA, long sB, long sC,
                int K, float scale)
{
  extern __shared__ char sm[];            // A: [0,65536) B: [65536,131072)
  const int t = threadIdx.x;
  const int lane = t & 63, wave = t >> 6;
  const int lm = lane & 15, quad = lane >> 4;
  const int wr = wave >> 2, wc = wave & 3;

  // T1: XCD-aware chunked remap within each z. grid.x*grid.y is 32 or 64
  // here (multiple of 8, and z-slices stay 8-aligned) -> bijective.
  const int gx = (int)gridDim.x;
  const int npz = gx * (int)gridDim.y;
  int lid = (int)blockIdx.x + gx * (int)blockIdx.y;
  lid = (lid & 7) * (npz >> 3) + (lid >> 3);
  const int bx = lid % gx, by = lid / gx;
  const int z = blockIdx.z;

  const char* Ab = (const char*)(A + (long)z * sA + (long)(by * 256) * lda);
  const char* Bb = (const char*)(B + (long)z * sB + (long)(bx * 256) * ldb);

  // staging: per K-tile 4 g2l16/thread (A half0, A half1, B half0, B half1).
  // LDS dest is LINEAR (wave base + lane*16); global source pre-swizzled.
  const int q0 = t * 16;
  const int ql = swz(q0);
  const int srow = ql >> 6, scb = ql & 63;     // logical row 0..127, col byte
  const char* pA0 = Ab + (long)srow * (lda * 2) + scb;
  const char* pA1 = pA0 + (long)128 * (lda * 2);
  const char* pB0 = Bb + (long)srow * (ldb * 2) + scb;
  const char* pB1 = pB0 + (long)128 * (ldb * 2);

  // ds_read offsets within a 16KB sub-tile (swizzled)
#define AOF(i) swz((wr * 128 + (i) * 16 + lm) * 64 + quad * 16)
#define BOF(j) swz((wc * 64 + (j) * 16 + lm) * 64 + quad * 16)
  const int aoff0 = AOF(0), aoff1 = AOF(1), aoff2 = AOF(2), aoff3 = AOF(3);
  const int aoff4 = AOF(4), aoff5 = AOF(5), aoff6 = AOF(6), aoff7 = AOF(7);
  const int boff0 = BOF(0), boff1 = BOF(1), boff2 = BOF(2), boff3 = BOF(3);

  f32x4 acc[8][4] = {};
  bf16x8 a0, a1, a2, a3, b0, b1, b2, b3;
  const int NT = K >> 5;

#define STAGE_A(tau) { char* d_ = sm + (((tau) & 3) << 14) + q0;              \
    g2l16(pA0, d_); g2l16(pA1, d_ + 8192); pA0 += 64; pA1 += 64; }
#define STAGE_B(tau) { char* d_ = sm + 65536 + (((tau) & 3) << 14) + q0;      \
    g2l16(pB0, d_); g2l16(pB1, d_ + 8192); pB0 += 64; pB1 += 64; }

#define MFMA4(I, AR)                                                          \
  acc[I][0] = __builtin_amdgcn_mfma_f32_16x16x32_bf16(AR, b0, acc[I][0], 0, 0, 0); \
  acc[I][1] = __builtin_amdgcn_mfma_f32_16x16x32_bf16(AR, b1, acc[I][1], 0, 0, 0); \
  acc[I][2] = __builtin_amdgcn_mfma_f32_16x16x32_bf16(AR, b2, acc[I][2], 0, 0, 0); \
  acc[I][3] = __builtin_amdgcn_mfma_f32_16x16x32_bf16(AR, b3, acc[I][3], 0, 0, 0);

  // Phase A: rows 0-3 quadrant. 8 ds_read_b128 || stage A-half of tau+3.
#define PHASE_A(tau, DO_STAGE) {                                              \
    char* Abuf_ = sm + (((tau) & 3) << 14);                                   \
    char* Bbuf_ = Abuf_ + 65536;                                              \
    a0 = *(const bf16x8*)(Abuf_ + aoff0);                                     \
    a1 = *(const bf16x8*)(Abuf_ + aoff1);                                     \
    a2 = *(const bf16x8*)(Abuf_ + aoff2);                                     \
    a3 = *(const bf16x8*)(Abuf_ + aoff3);                                     \
    b0 = *(const bf16x8*)(Bbuf_ + boff0);                                     \
    b1 = *(const bf16x8*)(Bbuf_ + boff1);                                     \
    b2 = *(const bf16x8*)(Bbuf_ + boff2);                                     \
    b3 = *(const bf16x8*)(Bbuf_ + boff3);                                     \
    if (DO_STAGE) STAGE_A((tau) + 3)                                          \
    __builtin_amdgcn_s_barrier();                                             \
    asm volatile("s_waitcnt lgkmcnt(0)" ::: "memory");                        \
    __builtin_amdgcn_s_setprio(1);                                            \
    MFMA4(0, a0) MFMA4(1, a1) MFMA4(2, a2) MFMA4(3, a3)                       \
    __builtin_amdgcn_s_setprio(0);                                            \
    __builtin_amdgcn_s_barrier();                                             \
  }

  // Phase B: rows 4-7 quadrant (B frags reused). 4 ds_read || stage B-half.
  // VM: counted vmcnt ("s_waitcnt vmcnt(8)" steady / 4 / 0 tail / "" last).
#define PHASE_B(tau, DO_STAGE, VM, ENDBAR) {                                  \
    char* Abuf_ = sm + (((tau) & 3) << 14);                                   \
    a0 = *(const bf16x8*)(Abuf_ + aoff4);                                     \
    a1 = *(const bf16x8*)(Abuf_ + aoff5);                                     \
    a2 = *(const bf16x8*)(Abuf_ + aoff6);                                     \
    a3 = *(const bf16x8*)(Abuf_ + aoff7);                                     \
    if (DO_STAGE) STAGE_B((tau) + 3)                                          \
    __builtin_amdgcn_s_barrier();                                             \
    asm volatile("s_waitcnt lgkmcnt(0)" ::: "memory");                        \
    __builtin_amdgcn_s_setprio(1);                                            \
    MFMA4(4, a0) MFMA4(5, a1) MFMA4(6, a2) MFMA4(7, a3)                       \
    __builtin_amdgcn_s_setprio(0);                                            \
    asm volatile(VM ::: "memory");                                            \
    if (ENDBAR) __builtin_amdgcn_s_barrier();                                 \
  }

  // Prologue: stage tiles 0,1,2; wait tile 0 (8 newest = tiles 1,2 in flight)
  STAGE_A(0) STAGE_B(0) STAGE_A(1) STAGE_B(1) STAGE_A(2) STAGE_B(2)
  asm volatile("s_waitcnt vmcnt(8)" ::: "memory");
  __builtin_amdgcn_s_barrier();

  for (int tau = 0; tau < NT - 3; ++tau) {
    PHASE_A(tau, 1)
    PHASE_B(tau, 1, "s_waitcnt vmcnt(8)", 1)
  }
  // Tail: 3 peeled K-tiles, drain 4 -> 0 -> none
  PHASE_A(NT - 3, 0)
  PHASE_B(NT - 3, 0, "s_waitcnt vmcnt(4)", 1)
  PHASE_A(NT - 2, 0)
  PHASE_B(NT - 2, 0, "s_waitcnt vmcnt(0)", 1)
  PHASE_A(NT - 1, 0)
  PHASE_B(NT - 1, 0, "", 0)

  // C/D layout (verified m89): col = lane&15, row = quad*4 + reg
  const int row0 = by * 256 + wr * 128 + quad * 4;
  const int col0 = bx * 256 + wc * 64 + lm;
  if (OUT_BF16) {
    u16* C = (u16*)Cv + (long)z * sC;
#pragma unroll
    for (int i = 0; i < 8; ++i)
#pragma unroll
      for (int j = 0; j < 4; ++j)
#pragma unroll
        for (int r = 0; r < 4; ++r)
          C[(long)(row0 + i * 16 + r) * ldc + (col0 + j * 16)] = f2bf(acc[i][j][r] * scale);
  } else {
    float* C = (float*)Cv + (long)z * sC;
#pragma unroll
    for (int i = 0; i < 8; ++i)
#pragma unroll
      for (int j = 0; j < 4; ++j)
#pragma unroll
        for (int r = 0; r < 4; ++r)
          C[(long)(row0 + i * 16 + r) * ldc + (col0 + j * 16)] = acc[i][j][r] * scale;
  }
}

// ---------------------------------------------------------------------------
// Row softmax over 2048 cols, in-place f32, plus bf16 copy to P
// ---------------------------------------------------------------------------
__global__ void softmax_rows(float* __restrict__ S, u16* __restrict__ P)
{
  const long row = blockIdx.x;
  float* p = S + row * 2048;
  u16*  q = P + row * 2048;
  const int t = threadIdx.x;
  float4 v0 = ((const float4*)p)[t];
  float4 v1 = ((const float4*)p)[t + 256];

  float m = fmaxf(fmaxf(fmaxf(v0.x, v0.y), fmaxf(v0.z, v0.w)),
                  fmaxf(fmaxf(v1.x, v1.y), fmaxf(v1.z, v1.w)));
#pragma unroll
  for (int s = 32; s; s >>= 1) m = fmaxf(m, __shfl_xor(m, s));
  __shared__ float red[4];
  if ((t & 63) == 0) red[t >> 6] = m;
  __syncthreads();
  m = fmaxf(fmaxf(red[0], red[1]), fmaxf(red[2], red[3]));

  v0.x = __expf(v0.x - m); v0.y = __expf(v0.y - m);
  v0.z = __expf(v0.z - m); v0.w = __expf(v0.w - m);
  v1.x = __expf(v1.x - m); v1.y = __expf(v1.y - m);
  v1.z = __expf(v1.z - m); v1.w = __expf(v1.w - m);

  float s8 = ((v0.x + v0.y) + (v0.z + v0.w)) + ((v1.x + v1.y) + (v1.z + v1.w));
#pragma unroll
  for (int s = 32; s; s >>= 1) s8 += __shfl_xor(s8, s);
  __syncthreads();
  if ((t & 63) == 0) red[t >> 6] = s8;
  __syncthreads();
  s8 = red[0] + red[1] + red[2] + red[3];
  const float inv = 1.0f / s8;

  v0.x *= inv; v0.y *= inv; v0.z *= inv; v0.w *= inv;
  v1.x *= inv; v1.y *= inv; v1.z *= inv; v1.w *= inv;
  ((float4*)p)[t] = v0;
  ((float4*)p)[t + 256] = v1;
  u16x4 b0 = { f2bf(v0.x), f2bf(v0.y), f2bf(v0.z), f2bf(v0.w) };
  u16x4 b1 = { f2bf(v1.x), f2bf(v1.y), f2bf(v1.z), f2bf(v1.w) };
  ((u16x4*)q)[t] = b0;
  ((u16x4*)q)[t + 256] = b1;
}

// ---------------------------------------------------------------------------
// Per-batch transpose f32[2048][1024] -> bf16[1024][2048]
// ---------------------------------------------------------------------------
__global__ void transpose_cvt(const float* __restrict__ in, u16* __restrict__ out)
{
  __shared__ float tile[32][33];
  const int z = blockIdx.z;
  const float* ib = in + (long)z * 2048 * 1024;
  u16* ob = out + (long)z * 1024 * 2048;
  const int c0 = blockIdx.x * 32, r0 = blockIdx.y * 32;
  const int tx = threadIdx.x, ty = threadIdx.y;
#pragma unroll
  for (int k = 0; k < 32; k += 8)
    tile[ty + k][tx] = ib[(long)(r0 + ty + k) * 1024 + c0 + tx];
  __syncthreads();
#pragma unroll
  for (int k = 0; k < 32; k += 8)
    ob[(long)(c0 + ty + k) * 2048 + r0 + tx] = f2bf(tile[tx][ty + k]);
}

// ---------------------------------------------------------------------------
// f32 -> bf16 convert with output row-stride ldo (input has 1024 cols)
// ---------------------------------------------------------------------------
__global__ void cvt_bf16(const float* __restrict__ in, u16* __restrict__ out,
                         int ldo, long n)
{
  long i = ((long)blockIdx.x * 256 + threadIdx.x) * 4;
  if (i >= n) return;
  float4 v = *(const float4*)(in + i);
  long row = i >> 10;
  int col = (int)(i & 1023);
  u16x4 b = { f2bf(v.x), f2bf(v.y), f2bf(v.z), f2bf(v.w) };
  *(u16x4*)(out + row * (long)ldo + col) = b;
}

extern "C" void kernel_launch(void* const* d_in, const int* in_sizes, int n_in,
                              void* d_out, int out_size, void* d_ws, size_t ws_size,
                              hipStream_t stream)
{
  (void)in_sizes; (void)n_in; (void)out_size; (void)ws_size;
  const float* query = (const float*)d_in[0];
  const float* bank  = (const float*)d_in[1];
  const float* Wc    = (const float*)d_in[2];
  const float* Woq   = (const float*)d_in[3];
  const float* Woc   = (const float*)d_in[4];

  const long B = 16, L = 2048, D = 1024;
  float* out  = (float*)d_out;                 // [B*L*D]
  float* attn = out + B * L * D;               // [B*L*L]

  // workspace layout (bytes): kb 67M | cpb 67M | kbT 67M | Acat 134M | Wcb 2M | Wcat 4M
  u16* kb   = (u16*)d_ws;                      // bf16(bank)           [B][L][D]
  u16* cpb  = kb + B * L * D;                  // bf16(ctx_proj)       [B][L][D]
  u16* ab   = kb;                              // bf16(attn) — reuses kb+cpb (dead after G2)
  u16* kbT  = cpb + B * L * D;                 // bf16(bank^T)         [B][D][L]
  u16* Acat = kbT + B * D * L;                 // [context | query]    [B][L][2048]
  u16* Wcb  = Acat + B * L * 2048;             // bf16(Wc)             [D][D]
  u16* Wcat = Wcb + D * D;                     // [Woc | Woq]          [D][2048]

  const long nQ = B * L * D;                   // 33.5M
  const long nW = D * D;                       // 1M

  // allow 128 KiB dynamic LDS for the pipelined GEMM (host-side, graph-safe)
  hipFuncSetAttribute(reinterpret_cast<const void*>(gemm_nt_8p<1>),
                      hipFuncAttributeMaxDynamicSharedMemorySize, 131072);
  hipFuncSetAttribute(reinterpret_cast<const void*>(gemm_nt_8p<0>),
                      hipFuncAttributeMaxDynamicSharedMemorySize, 131072);

  cvt_bf16<<<dim3((unsigned)(nQ / 4 / 256)), 256, 0, stream>>>(bank, kb, 1024, nQ);
  cvt_bf16<<<dim3((unsigned)(nQ / 4 / 256)), 256, 0, stream>>>(query, Acat + 1024, 2048, nQ);
  cvt_bf16<<<dim3((unsigned)(nW / 4 / 256)), 256, 0, stream>>>(Wc, Wcb, 1024, nW);
  cvt_bf16<<<dim3((unsigned)(nW / 4 / 256)), 256, 0, stream>>>(Woc, Wcat, 2048, nW);
  cvt_bf16<<<dim3((unsigned)(nW / 4 / 256)), 256, 0, stream>>>(Woq, Wcat + 1024, 2048, nW);
  transpose_cvt<<<dim3(32, 64, 16), dim3(32, 8), 0, stream>>>(bank, kbT);

  // G1: cpb[b] = kb[b] @ Wcb^T          M=2048 N=1024 K=1024
  gemm_nt_8p<1><<<dim3(4, 8, 16), 512, 131072, stream>>>(kb, Wcb, cpb,
      1024, 1024, 1024, L * D, 0, L * D, 1024, 1.0f);
  // G2: S[b] = query[b] @ cpb[b]^T / 32  M=2048 N=2048 K=1024  (A = query half of Acat)
  gemm_nt_8p<0><<<dim3(8, 8, 16), 512, 131072, stream>>>(Acat + 1024, cpb, attn,
      2048, 1024, 2048, L * 2048, L * D, L * 2048, 1024, 0.03125f);
  // softmax rows -> attn (f32, in place) + ab (bf16)
  softmax_rows<<<dim3((unsigned)(B * L)), 256, 0, stream>>>(attn, ab);
  // G4: context[b] = ab[b] @ bank[b]  (as NT vs kbT)  M=2048 N=1024 K=2048 -> Acat cols 0:1023
  gemm_nt_8p<1><<<dim3(4, 8, 16), 512, 131072, stream>>>(ab, kbT, Acat,
      2048, 2048, 2048, L * 2048, D * 2048, L * 2048, 2048, 1.0f);
  // G5: out[b] = Acat[b] @ Wcat^T       M=2048 N=1024 K=2048
  gemm_nt_8p<0><<<dim3(4, 8, 16), 512, 131072, stream>>>(Acat, Wcat, out,
      2048, 2048, 1024, L * 2048, 0, L * D, 2048, 1.0f);
}